// Round 11
// baseline (107.912 us; speedup 1.0000x reference)
//
#include <hip/hip_runtime.h>
#include <hip/hip_bf16.h>
#include <float.h>
#include <math.h>

#define CDIM 128

typedef __attribute__((ext_vector_type(8))) short short8v;   // 8 bf16 = 1 MFMA A/B frag
typedef __attribute__((ext_vector_type(4))) short short4v;   // 4 bf16 (8B LDS store)
typedef __attribute__((ext_vector_type(4))) float f32x4;     // MFMA C/D frag

__device__ __forceinline__ short bf16b(float f) {
    __hip_bfloat16 h = __float2bfloat16(f);
    return __builtin_bit_cast(short, h);
}

// fast tanh via hardware exp: tanh(y) = 1 - 2/(exp(2y)+1)
__device__ __forceinline__ float tanh_fast(float y) {
    float e = __expf(2.0f * y);
    return 1.0f - 2.0f / (e + 1.0f);
}

__device__ __forceinline__ int lower_bound_i(const int* __restrict__ b, int n, int v) {
    int lo = 0, hi = n;
    while (lo < hi) { int mid = (lo + hi) >> 1; if (b[mid] < v) lo = mid + 1; else hi = mid; }
    return lo;
}

// Fused prep: blocks 0..7 pack proj_w into bf16 MFMA fragments
// (frag f=ct*4+ks, lane l: chan c=ct*16+(l&15), k=ks*32+(l>>4)*8+j);
// blocks 8.. compute per-graph boundaries by binary search.
__global__ void prep_kernel(const float* __restrict__ proj_w, short* __restrict__ wfrag,
                            const int* __restrict__ batch, int N, int G,
                            int* __restrict__ seg) {
    const int b = blockIdx.x;
    if (b < 8) {
        int tid = b * 256 + threadIdx.x;            // 0..2047
        int f = tid >> 6, l = tid & 63;
        int c  = ((f >> 2) << 4) | (l & 15);
        int k0 = ((f & 3) << 5) | ((l >> 4) << 3);
        short8v v;
        #pragma unroll
        for (int j = 0; j < 8; ++j) v[j] = bf16b(proj_w[c * CDIM + k0 + j]);
        ((short8v*)wfrag)[tid] = v;
    } else {
        int g = (b - 8) * 256 + threadIdx.x;
        if (g < G) seg[g] = lower_bound_i(batch, N, g);
        if (g == 0) seg[G] = N;
    }
}

// One block (4 waves) per graph — R10 skeleton (swapped-operand MFMA, in-lane
// epilogue, wave0 softmax, register pooling) with CLAMP-FREE addressing:
//   chunk base = min(start+cb, N-64) is UNIFORM -> per-thread load index is a
//   compile-time constant off an incrementing base pointer (SGPR-friendly,
//   zero per-chunk address VALU). Tail validity is one unsigned compare in
//   the wave0 softmax mask; over-read rows are valid memory weighted by e=0.
__launch_bounds__(256, 4)
__global__ void pool_kernel(const float* __restrict__ x,
                            const short* __restrict__ wfrag,
                            const float* __restrict__ proj_b,
                            const float* __restrict__ score_w,
                            const float* __restrict__ score_b,
                            const int* __restrict__ seg,
                            float* __restrict__ out,
                            int N) {
    // LDS: 16KB XsB + 5.1KB ps + cs/bc ≈ 21.4KB
    __shared__ __align__(16) short XsB[64 * 128]; // bf16: row*128 + (k ^ ((row&7)<<3))
    __shared__ float ps[64 * 20];                 // partials [row][w*4+kq], stride 20
    __shared__ float cs[64];                      // exp weights (LDS-row indexed)
    __shared__ float bc[2];                       // {scale, chunk exp-sum}

    const int g = blockIdx.x;
    const int t = threadIdx.x;
    const int lane = t & 63;
    const int w = t >> 6;                     // wave id: owns chan-tiles 2w, 2w+1
    const int start = seg[g];
    const int cnt = seg[g + 1] - start;
    float4* og4 = (float4*)(out + (size_t)g * CDIM);

    if (cnt <= 0) {                           // empty graph pools to zeros
        if (t < 32) og4[t] = make_float4(0.f, 0.f, 0.f, 0.f);
        return;
    }

    // W fragments for this wave's 2 channel-tiles: 8 frags = 32 VGPR
    short8v wf[2][4];
    {
        const short8v* wfg = (const short8v*)wfrag;
        #pragma unroll
        for (int j = 0; j < 2; ++j)
            #pragma unroll
            for (int ks = 0; ks < 4; ++ks)
                wf[j][ks] = wfg[((((w << 1) | j) << 2 | ks) << 6) | lane];
    }
    const int al = lane & 15, kq = lane >> 4;
    // per-lane score/bias slices: chans (2w+j)*16 + kq*4 + r
    float4 swl4[2], pbl4[2];
    #pragma unroll
    for (int j = 0; j < 2; ++j) {
        swl4[j] = *(const float4*)&score_w[((((w << 1) | j) << 4) | (kq << 2))];
        pbl4[j] = *(const float4*)&proj_b[((((w << 1) | j) << 4) | (kq << 2))];
    }
    const float sb = score_b[0];

    const float4* __restrict__ x4 = (const float4*)x;
    const int g8 = t >> 5;                    // stage/pool row phase (0..7)
    const int c4 = t & 31;                    // float4 column slot
    const int lidx = (g8 << 5) | c4;          // per-thread constant load index base

    float m_run = -FLT_MAX, l_run = 0.0f;
    float4 pa = make_float4(0.f, 0.f, 0.f, 0.f);

    for (int cb = 0; cb < cnt; cb += 64) {
        const int rem = cnt - cb;             // >=1
        const int base = min(start + cb, N - 64);   // uniform: no per-lane clamp
        const int lo = start + cb - base;           // valid LDS rows: [lo, lo+rem)
        const float4* pb = x4 + (size_t)base * 32;

        // ---- load 64 rows: zero per-chunk address VALU (constant offsets) ----
        float4 xr[8];
        #pragma unroll
        for (int i = 0; i < 8; ++i)
            xr[i] = pb[(i << 8) | lidx];      // row = g8+8i, idx = row*32+c4

        // ---- stage bf16 swizzled LDS (converted ONCE; fp32 stays in regs) ----
        #pragma unroll
        for (int i = 0; i < 8; ++i) {
            int row = g8 + (i << 3);
            short4v b;
            b[0] = bf16b(xr[i].x); b[1] = bf16b(xr[i].y);
            b[2] = bf16b(xr[i].z); b[3] = bf16b(xr[i].w);
            *(short4v*)&XsB[(row << 7) | ((c4 << 2) ^ ((row & 7) << 3))] = b;
        }
        __syncthreads();                      // sync1: XsB ready (prev readers done)

        // ---- per row-tile: 8 MFMA (swapped) + in-lane tanh/score, 0 shuffles ----
        #pragma unroll
        for (int rt = 0; rt < 4; ++rt) {
            const int arow = (rt << 4) | al;
            const int rsw = (arow & 7) << 3;
            short8v xf[4];
            #pragma unroll
            for (int ks = 0; ks < 4; ++ks)
                xf[ks] = *(const short8v*)&XsB[(arow << 7) | (((ks << 5) | (kq << 3)) ^ rsw)];
            f32x4 a0 = (f32x4){0.f, 0.f, 0.f, 0.f};
            f32x4 a1 = (f32x4){0.f, 0.f, 0.f, 0.f};
            #pragma unroll
            for (int ks = 0; ks < 4; ++ks) {
                a0 = __builtin_amdgcn_mfma_f32_16x16x32_bf16(wf[0][ks], xf[ks], a0, 0, 0, 0);
                a1 = __builtin_amdgcn_mfma_f32_16x16x32_bf16(wf[1][ks], xf[ks], a1, 0, 0, 0);
            }
            // D[m=chan=(2w+j)*16+kq*4+r][n=row=rt*16+al]: in-lane dot over 8 chans
            float scp = 0.f;
            #pragma unroll
            for (int r = 0; r < 4; ++r) {
                scp += swl4[0][r] * tanh_fast(a0[r] + pbl4[0][r]);
                scp += swl4[1][r] * tanh_fast(a1[r] + pbl4[1][r]);
            }
            ps[((rt << 4) | al) * 20 + ((w << 2) | kq)] = scp;
        }
        __syncthreads();                      // sync2: ps complete, XsB reads done

        // ---- wave0 softmax: sum 16 partials per row + 12 shuffles ----
        if (t < 64) {
            const bool valid = (unsigned)(t - lo) < (unsigned)rem;
            float sv = -FLT_MAX;
            if (valid) {
                const float* p = &ps[t * 20];
                float4 q0 = *(const float4*)&p[0],  q1 = *(const float4*)&p[4];
                float4 q2 = *(const float4*)&p[8],  q3 = *(const float4*)&p[12];
                sv = ((q0.x + q0.y) + (q0.z + q0.w)) + ((q1.x + q1.y) + (q1.z + q1.w))
                   + ((q2.x + q2.y) + (q2.z + q2.w)) + ((q3.x + q3.y) + (q3.z + q3.w)) + sb;
            }
            float mx = sv;
            #pragma unroll
            for (int m = 1; m < 64; m <<= 1) mx = fmaxf(mx, __shfl_xor(mx, m));
            const float m_new = fmaxf(m_run, mx);
            float e = valid ? __expf(sv - m_new) : 0.f;
            float ssum = e;
            #pragma unroll
            for (int m = 1; m < 64; m <<= 1) ssum += __shfl_xor(ssum, m);
            cs[t] = e;
            if (t == 0) { bc[0] = __expf(m_run - m_new); bc[1] = ssum; }
            m_run = m_new;                    // wave0-private running max
        }
        __syncthreads();                      // sync3: cs/bc ready

        // ---- rescale + pooling accumulate (registers + cs broadcast) ----
        const float sc = bc[0];
        l_run = l_run * sc + bc[1];
        pa.x *= sc; pa.y *= sc; pa.z *= sc; pa.w *= sc;
        #pragma unroll
        for (int i = 0; i < 8; ++i) {
            float em = cs[g8 + (i << 3)];             // 0 for invalid rows
            pa.x += em * xr[i].x; pa.y += em * xr[i].y;
            pa.z += em * xr[i].z; pa.w += em * xr[i].w;
        }
    }

    // ---- cross-phase reduce (alias red onto XsB) + normalize + store ----
    float* red = (float*)XsB;                 // safe: XsB reads ended at last sync2
    *(float4*)&red[(g8 << 7) + (c4 << 2)] = pa;
    __syncthreads();
    if (t < 32) {
        float4 v = make_float4(0.f, 0.f, 0.f, 0.f);
        #pragma unroll
        for (int j = 0; j < 8; ++j) {
            float4 r = *(const float4*)&red[(j << 7) + (t << 2)];
            v.x += r.x; v.y += r.y; v.z += r.z; v.w += r.w;
        }
        const float inv = 1.0f / fmaxf(l_run, 1e-30f);
        v.x *= inv; v.y *= inv; v.z *= inv; v.w *= inv;
        og4[t] = v;
    }
}

extern "C" void kernel_launch(void* const* d_in, const int* in_sizes, int n_in,
                              void* d_out, int out_size, void* d_ws, size_t ws_size,
                              hipStream_t stream) {
    const float* x       = (const float*)d_in[0];
    const float* proj_w  = (const float*)d_in[1];
    const float* proj_b  = (const float*)d_in[2];
    const float* score_w = (const float*)d_in[3];
    const float* score_b = (const float*)d_in[4];
    const int*   batch   = (const int*)d_in[5];

    const int N = in_sizes[0] / CDIM;
    const int G = out_size / CDIM;

    int*   seg   = (int*)d_ws;
    short* wfrag = (short*)((char*)d_ws + (((size_t)(G + 1) * 4 + 255) & ~(size_t)255));

    prep_kernel<<<8 + (G + 255) / 256, 256, 0, stream>>>(proj_w, wfrag, batch, N, G, seg);
    pool_kernel<<<G, 256, 0, stream>>>(x, wfrag, proj_b, score_w, score_b,
                                       seg, (float*)d_out, N);
}